// Round 7
// baseline (393.272 us; speedup 1.0000x reference)
//
#include <hip/hip_runtime.h>
#include <hip/hip_bf16.h>
#include <math.h>

#define B_SZ    2
#define LSEQ    1024
#define D_MODEL 2048
#define D_INNER 4096
#define D_STATE 16
#define DT_RANK 128
#define M_TOK   (B_SZ * LSEQ)      // 2048 token rows
#define NCHUNK  16
#define LCHUNK  (LSEQ / NCHUNK)    // 64

typedef __attribute__((ext_vector_type(8))) short bf16x8;
typedef __attribute__((ext_vector_type(4))) float f32x4;

__device__ __forceinline__ float softplusf_(float x) {
    return fmaxf(x, 0.f) + log1pf(expf(-fabsf(x)));
}
__device__ __forceinline__ unsigned f2bf(float f) {
    union { float f; unsigned u; } v; v.f = f;
    const unsigned u = v.u;
    return (u + 0x7fffu + ((u >> 16) & 1u)) >> 16;   // RNE, finite inputs
}
__device__ __forceinline__ float bf2f(unsigned u) {
    union { unsigned u; float f; } v; v.u = u << 16; return v.f;
}
__device__ __forceinline__ void gload16(const void* g, void* lds) {
    __builtin_amdgcn_global_load_lds(
        (const __attribute__((address_space(1))) void*)g,
        (__attribute__((address_space(3))) void*)lds, 16, 0, 0);
}

// ---------------------------------------------------------------------------
// bf16 MFMA GEMM: C[M,N] = A[M,K](bf16) * B[N,K](bf16)^T, fp32 acc.
// 128x128 tile, BK=32, 256 thr (4 waves 2x2). RING-3 LDS buffers (48 KB ->
// 3 blocks/CU) with DEPTH-2 counted prefetch: iter kt stages tile kt+2,
// waits vmcnt(8) (tile kt complete, 8 loads of kt+1/kt+2 stay in flight).
// Race ledger: iter kt writes buf[(kt+2)%3] and reads buf[kt%3] (disjoint);
// the overwritten tile kt-1 was consumed before iter kt-1's trailing
// s_barrier; vmcnt retires in issue order (m135). sched_barrier(0) after
// each s_barrier fences compiler motion (rule #18).
// LDS: [128][32] bf16 rows of 4x16B chunks; read chunk = lh ^ ((row>>1)&3)
// (2-way bank aliasing = free, m136); staging SOURCE pre-swizzled with the
// same involution, linear wave-uniform dest (both-sides rule m104/m231).
// XCD-aware bijective block swizzle on the x-y grid (all grids nwg%8==0).
// Split-K via gridDim.z (C += z*zstride).
// epi: 0 = f32 store; 1 = softplus(v+bias[col]) -> bf16; 5 = dual bf16
// (col<4096 -> Cv bf16 ld 4096, col>=4096 -> Cv2 bf16 ld 4096).
// ---------------------------------------------------------------------------
__global__ __launch_bounds__(256, 3)
void gemm_bf16_bt(const ushort* __restrict__ A, int lda,
                  const ushort* __restrict__ B, int ldb,
                  void* __restrict__ Cv, int ldc,
                  void* __restrict__ Cv2,
                  const float* __restrict__ bias,
                  int M, int N, int K, int epi, size_t zstride)
{
    __shared__ ushort As[3][128 * 32];
    __shared__ ushort Bs[3][128 * 32];
    const int t = threadIdx.x;

    // bijective XCD swizzle over the x-y plane (requires nwg % 8 == 0)
    const int nwg = gridDim.x * gridDim.y;
    int wg = blockIdx.x + gridDim.x * blockIdx.y;
    wg = (wg & 7) * (nwg >> 3) + (wg >> 3);
    const int bx = wg % gridDim.x, by = wg / gridDim.x;
    const int bm = by << 7, bn = bx << 7;

    const int wave = t >> 6, lane = t & 63;
    const int wr   = (wave >> 1) << 6, wc = (wave & 1) << 6;
    const int lr   = lane & 15, lh = lane >> 4;
    const int kper  = K / gridDim.z;
    const int kbase = blockIdx.z * kper;
    const int nkt   = kper >> 5;           // BK=32

    // staging: seg = it*4+wave (8 segs x 64 chunks); chunk c = seg*64+lane;
    // row = c>>2, j = c&3; source column jj = j ^ ((row>>1)&3)
    const ushort* ga[2]; const ushort* gb[2];
    int ldof[2];
#pragma unroll
    for (int it = 0; it < 2; ++it) {
        const int seg = (it << 2) + wave;
        const int c   = (seg << 6) + lane;
        const int row = c >> 2, j = c & 3;
        const int jj  = j ^ ((row >> 1) & 3);
        ga[it] = A + (size_t)(bm + row) * lda + kbase + jj * 8;
        int gn = bn + row; gn = gn < N ? gn : N - 1;
        gb[it] = B + (size_t)gn * ldb + kbase + jj * 8;
        ldof[it] = seg << 9;               // ushort offset: seg*512
    }

#define STAGE(bi) do {                                                  \
    _Pragma("unroll")                                                   \
    for (int it = 0; it < 2; ++it) {                                    \
        gload16(ga[it], &As[bi][ldof[it]]);                             \
        gload16(gb[it], &Bs[bi][ldof[it]]);                             \
        ga[it] += 32; gb[it] += 32;                                     \
    }                                                                   \
} while (0)

    f32x4 acc[4][4];
#pragma unroll
    for (int i = 0; i < 4; ++i)
#pragma unroll
        for (int j = 0; j < 4; ++j) {
            acc[i][j][0] = 0.f; acc[i][j][1] = 0.f;
            acc[i][j][2] = 0.f; acc[i][j][3] = 0.f;
        }

    STAGE(0);                               // tile 0
    STAGE(1);                               // tile 1   (8 loads in flight)
    int cur = 0, stg = 2;
    for (int kt = 0; kt < nkt; ++kt) {
        const int rem = nkt - 1 - kt;
        if (rem >= 2) {
            STAGE(stg);                     // tile kt+2 -> 12 in flight
            stg = (stg == 2) ? 0 : stg + 1;
            asm volatile("s_waitcnt vmcnt(8)" ::: "memory");   // tile kt done
        } else if (rem == 1) {
            asm volatile("s_waitcnt vmcnt(4)" ::: "memory");
        } else {
            asm volatile("s_waitcnt vmcnt(0)" ::: "memory");
        }
        __builtin_amdgcn_s_barrier();       // tile kt staged by all waves
        __builtin_amdgcn_sched_barrier(0);

        const char* Ab = (const char*)As[cur];
        const char* Bb = (const char*)Bs[cur];
        bf16x8 af[4], bf[4];
#pragma unroll
        for (int mi = 0; mi < 4; ++mi) {
            const int row = wr + (mi << 4) + lr;
            const int ch  = lh ^ ((row >> 1) & 3);
            af[mi] = *(const bf16x8*)(Ab + row * 64 + (ch << 4));
        }
#pragma unroll
        for (int nj = 0; nj < 4; ++nj) {
            const int row = wc + (nj << 4) + lr;
            const int ch  = lh ^ ((row >> 1) & 3);
            bf[nj] = *(const bf16x8*)(Bb + row * 64 + (ch << 4));
        }
#pragma unroll
        for (int mi = 0; mi < 4; ++mi)
#pragma unroll
            for (int nj = 0; nj < 4; ++nj)
                acc[mi][nj] = __builtin_amdgcn_mfma_f32_16x16x32_bf16(
                    af[mi], bf[nj], acc[mi][nj], 0, 0, 0);

        cur = (cur == 2) ? 0 : cur + 1;
        __builtin_amdgcn_s_barrier();       // all waves done reading buf[cur]
        __builtin_amdgcn_sched_barrier(0);
    }
#undef STAGE

    float*  C  = (float*)Cv + (size_t)blockIdx.z * zstride;
    ushort* Cb = (ushort*)Cv;
    ushort* C2 = (ushort*)Cv2;
#pragma unroll
    for (int mi = 0; mi < 4; ++mi) {
#pragma unroll
        for (int nj = 0; nj < 4; ++nj) {
            const int col  = bn + wc + (nj << 4) + lr;
            const int row0 = bm + wr + (mi << 4) + (lh << 2);
            if (col < N) {
#pragma unroll
                for (int r = 0; r < 4; ++r) {
                    const float v = acc[mi][nj][r];
                    if (epi == 0) {
                        C[(size_t)(row0 + r) * ldc + col] = v;
                    } else if (epi == 1) {
                        Cb[(size_t)(row0 + r) * ldc + col] =
                            (ushort)f2bf(softplusf_(v + bias[col]));
                    } else {  // epi == 5: dual bf16 store (fused in_proj)
                        if (col < D_INNER)
                            Cb[(size_t)(row0 + r) * ldc + col] = (ushort)f2bf(v);
                        else
                            C2[(size_t)(row0 + r) * ldc + (col - D_INNER)] = (ushort)f2bf(v);
                    }
                }
            }
        }
    }
}

// ---------------------------------------------------------------------------
__global__ __launch_bounds__(256)
void cvt_bf16(const float* __restrict__ in, ushort* __restrict__ out, int n8)
{
    for (int i = blockIdx.x * 256 + threadIdx.x; i < n8; i += gridDim.x * 256) {
        const float4 v0 = ((const float4*)in)[i * 2];
        const float4 v1 = ((const float4*)in)[i * 2 + 1];
        int4 p;
        p.x = (int)(f2bf(v0.x) | (f2bf(v0.y) << 16));
        p.y = (int)(f2bf(v0.z) | (f2bf(v0.w) << 16));
        p.z = (int)(f2bf(v1.x) | (f2bf(v1.y) << 16));
        p.w = (int)(f2bf(v1.z) | (f2bf(v1.w) << 16));
        ((int4*)out)[i] = p;
    }
}

// ---------------------------------------------------------------------------
__global__ __launch_bounds__(256)
void reduce_out(const float* __restrict__ part, float* __restrict__ out, int n4)
{
    for (int i = blockIdx.x * 256 + threadIdx.x; i < n4; i += gridDim.x * 256) {
        const float4 a = ((const float4*)part)[i];
        const float4 b = ((const float4*)(part + (size_t)M_TOK * D_MODEL))[i];
        ((float4*)out)[i] = make_float4(a.x + b.x, a.y + b.y, a.z + b.z, a.w + b.w);
    }
}

// ---------------------------------------------------------------------------
// Depthwise causal conv (K=4) + bias + SiLU. xraw bf16 [M][4096] -> xt bf16.
// ---------------------------------------------------------------------------
__global__ __launch_bounds__(256)
void conv_silu_k(const ushort* __restrict__ xraw,
                 const float* __restrict__ cw,
                 const float* __restrict__ cb,
                 ushort* __restrict__ xb)
{
    const int d = (blockIdx.x << 8) + threadIdx.x;
    const int m = blockIdx.y;
    const int l = m & (LSEQ - 1);
    const float4 w = *(const float4*)&cw[d << 2];
    const float wv[4] = {w.x, w.y, w.z, w.w};
    float acc = cb[d];
#pragma unroll
    for (int j = 0; j < 4; ++j) {
        const int ls = l - 3 + j;
        if (ls >= 0)
            acc = fmaf(wv[j], bf2f(xraw[(size_t)(m - 3 + j) * D_INNER + d]), acc);
    }
    const float sg = 1.f / (1.f + expf(-acc));
    xb[(size_t)m * D_INNER + d] = (ushort)f2bf(acc * sg);
}

// ---------------------------------------------------------------------------
__global__ __launch_bounds__(256)
void reduce_ssm(const float* __restrict__ part,
                float* __restrict__ ssmf, ushort* __restrict__ ssmb)
{
    const int i = blockIdx.x * 256 + threadIdx.x;   // < 2048*160
    float v = 0.f;
#pragma unroll
    for (int z = 0; z < 8; ++z) v += part[(size_t)z * (M_TOK * 160) + i];
    ssmf[i] = v;
    ssmb[i] = (ushort)f2bf(v);
}

// ---------------------------------------------------------------------------
// Chunked selective scan: thread owns (b, d, chunk), 16 states in VGPRs.
// ---------------------------------------------------------------------------
__global__ __launch_bounds__(256)
void scan_pass1(const ushort* __restrict__ dtp,   // dt bf16 [M][4096]
                const ushort* __restrict__ xb,    // x bf16 [M][4096]
                const float* __restrict__ ssm,    // [M][160], B @ 128+s
                const float* __restrict__ Ap,     // [4096][16]
                float* __restrict__ Pc, float* __restrict__ Qc)
{
    const int d = (blockIdx.x << 8) + threadIdx.x;
    const int c = blockIdx.y, b = blockIdx.z;
    float a[16];
    *(float4*)&a[0]  = *(const float4*)&Ap[d * 16];
    *(float4*)&a[4]  = *(const float4*)&Ap[d * 16 + 4];
    *(float4*)&a[8]  = *(const float4*)&Ap[d * 16 + 8];
    *(float4*)&a[12] = *(const float4*)&Ap[d * 16 + 12];
    float q[16];
#pragma unroll
    for (int s = 0; s < 16; ++s) q[s] = 0.f;
    float dtsum = 0.f;
    const size_t m0 = (size_t)b * LSEQ + (size_t)c * LCHUNK;
#pragma unroll 2
    for (int l = 0; l < LCHUNK; ++l) {
        const size_t m = m0 + l;
        const float dt = bf2f(dtp[m * D_INNER + d]);
        const float xv = bf2f(xb[m * D_INNER + d]);
        const float4 B0 = *(const float4*)&ssm[m * 160 + 128];
        const float4 B1 = *(const float4*)&ssm[m * 160 + 132];
        const float4 B2 = *(const float4*)&ssm[m * 160 + 136];
        const float4 B3 = *(const float4*)&ssm[m * 160 + 140];
        const float Bv[16] = {B0.x,B0.y,B0.z,B0.w, B1.x,B1.y,B1.z,B1.w,
                              B2.x,B2.y,B2.z,B2.w, B3.x,B3.y,B3.z,B3.w};
        const float t1 = dt * xv;
#pragma unroll
        for (int s = 0; s < 16; ++s) {
            const float dA = __expf(dt * a[s]);
            q[s] = fmaf(q[s], dA, t1 * Bv[s]);
        }
        dtsum += dt;
    }
    const size_t o = (((size_t)b * D_INNER + d) * NCHUNK + c) * D_STATE;
    float P[16];
#pragma unroll
    for (int s = 0; s < 16; ++s) P[s] = __expf(a[s] * dtsum);
#pragma unroll
    for (int s4 = 0; s4 < 4; ++s4) {
        *(float4*)&Pc[o + s4 * 4] = make_float4(P[s4*4], P[s4*4+1], P[s4*4+2], P[s4*4+3]);
        *(float4*)&Qc[o + s4 * 4] = make_float4(q[s4*4], q[s4*4+1], q[s4*4+2], q[s4*4+3]);
    }
}

__global__ __launch_bounds__(256)
void scan_pass2(const float* __restrict__ Pc, float* __restrict__ Qc)
{
    const int i = blockIdx.x * 256 + threadIdx.x;   // (b*4096+d)*16+s
    const size_t base = (size_t)(i >> 4) * (NCHUNK * D_STATE) + (i & 15);
    float st = 0.f;
#pragma unroll
    for (int c = 0; c < NCHUNK; ++c) {
        const float P = Pc[base + c * D_STATE];
        const float q = Qc[base + c * D_STATE];
        Qc[base + c * D_STATE] = st;    // state entering chunk c
        st = fmaf(st, P, q);
    }
}

__global__ __launch_bounds__(256)
void scan_pass3(const ushort* __restrict__ dtp,   // dt bf16
                ushort* __restrict__ xb,          // x bf16 in / y bf16 out
                const ushort* __restrict__ gb,    // gate bf16
                const float* __restrict__ ssm,
                const float* __restrict__ Ap,
                const float* __restrict__ Qc,
                const float* __restrict__ Dp)
{
    const int d = (blockIdx.x << 8) + threadIdx.x;
    const int c = blockIdx.y, b = blockIdx.z;
    float a[16], st[16];
    *(float4*)&a[0]  = *(const float4*)&Ap[d * 16];
    *(float4*)&a[4]  = *(const float4*)&Ap[d * 16 + 4];
    *(float4*)&a[8]  = *(const float4*)&Ap[d * 16 + 8];
    *(float4*)&a[12] = *(const float4*)&Ap[d * 16 + 12];
    const size_t qo = (((size_t)b * D_INNER + d) * NCHUNK + c) * D_STATE;
    *(float4*)&st[0]  = *(const float4*)&Qc[qo];
    *(float4*)&st[4]  = *(const float4*)&Qc[qo + 4];
    *(float4*)&st[8]  = *(const float4*)&Qc[qo + 8];
    *(float4*)&st[12] = *(const float4*)&Qc[qo + 12];
    const float Dd = Dp[d];
    const size_t m0 = (size_t)b * LSEQ + (size_t)c * LCHUNK;
#pragma unroll 2
    for (int l = 0; l < LCHUNK; ++l) {
        const size_t m = m0 + l;
        const float dt = bf2f(dtp[m * D_INNER + d]);
        const float xv = bf2f(xb[m * D_INNER + d]);
        const float gv = bf2f(gb[m * D_INNER + d]);
        const float4 B0 = *(const float4*)&ssm[m * 160 + 128];
        const float4 B1 = *(const float4*)&ssm[m * 160 + 132];
        const float4 B2 = *(const float4*)&ssm[m * 160 + 136];
        const float4 B3 = *(const float4*)&ssm[m * 160 + 140];
        const float4 C0 = *(const float4*)&ssm[m * 160 + 144];
        const float4 C1 = *(const float4*)&ssm[m * 160 + 148];
        const float4 C2 = *(const float4*)&ssm[m * 160 + 152];
        const float4 C3 = *(const float4*)&ssm[m * 160 + 156];
        const float Bv[16] = {B0.x,B0.y,B0.z,B0.w, B1.x,B1.y,B1.z,B1.w,
                              B2.x,B2.y,B2.z,B2.w, B3.x,B3.y,B3.z,B3.w};
        const float Cv[16] = {C0.x,C0.y,C0.z,C0.w, C1.x,C1.y,C1.z,C1.w,
                              C2.x,C2.y,C2.z,C2.w, C3.x,C3.y,C3.z,C3.w};
        const float t1 = dt * xv;
        float y = 0.f;
#pragma unroll
        for (int s = 0; s < 16; ++s) {
            const float dA = __expf(dt * a[s]);
            st[s] = fmaf(st[s], dA, t1 * Bv[s]);
            y = fmaf(st[s], Cv[s], y);
        }
        const float yg  = fmaf(Dd, xv, y);
        const float sig = 1.f / (1.f + expf(-gv));
        xb[m * D_INNER + d] = (ushort)f2bf(yg * (gv * sig));
    }
}

// ---------------------------------------------------------------------------
extern "C" void kernel_launch(void* const* d_in, const int* in_sizes, int n_in,
                              void* d_out, int out_size, void* d_ws, size_t ws_size,
                              hipStream_t stream)
{
    (void)in_sizes; (void)n_in; (void)out_size; (void)ws_size;
    const float* hs  = (const float*)d_in[0];  // [2048,2048]
    const float* inw = (const float*)d_in[1];  // [8192,2048]
    const float* cw  = (const float*)d_in[2];  // [4096,4]
    const float* cb  = (const float*)d_in[3];  // [4096]
    const float* xw  = (const float*)d_in[4];  // [160,4096]
    const float* dtw = (const float*)d_in[5];  // [4096,128]
    const float* dtb = (const float*)d_in[6];  // [4096]
    const float* Ap  = (const float*)d_in[7];  // [4096,16]
    const float* Dp  = (const float*)d_in[8];  // [4096]
    const float* ow  = (const float*)d_in[9];  // [2048,4096]
    float* out = (float*)d_out;                // [2048,2048]

    // ------------------------------------------------------------------
    // Workspace layout, f32-offset units (bf16 sizes are f32-EQUIV =
    // ushort_count/2). Total 24,150,016 f32 = 96.6 MB. Same as round 6
    // (proven correct): single-writer-before-reader on the launch timeline.
    // ------------------------------------------------------------------
    float*  ws    = (float*)d_ws;
    ushort* pg    = (ushort*)(ws + 0);          // gate bf16 [2048][4096]
    ushort* xraw  = (ushort*)(ws + 4194304);    // x bf16 pre-conv
    ushort* xtb   = (ushort*)(ws + 8388608);    // xt bf16 -> y bf16
    float*  ssmf  = ws + 12582912;              // f32 [2048][160]
    ushort* ssmb  = (ushort*)(ws + 12910592);   // bf16 [2048][160]
    ushort* xwb   = (ushort*)(ws + 13074432);   // bf16 [160][4096]
    ushort* dtwb  = (ushort*)(ws + 13402112);   // bf16 [4096][128]
    ushort* hsb   = (ushort*)(ws + 13664256);   // bf16 [2048][2048]
    ushort* inwb  = (ushort*)(ws + 15761408);   // bf16 [8192][2048]
    ushort* owb   = (ushort*)(ws + 15761408);   // alias: after in_proj
    float*  part  = ws + 19955712;              // x_proj partials, dead by dt_proj
    ushort* dtb16 = (ushort*)(ws + 19955712);   // alias: after reduce_ssm
    float*  Pc    = ws + 4194304;               // alias: after conv (xraw dead)
    float*  Qc    = ws + 6291456;
    float*  opart = ws + 0;                     // alias: after scan_pass3

    const dim3 blk(256);

    // conversions
    cvt_bf16<<<dim3(1280), blk, 0, stream>>>(hs,  hsb,  524288);
    cvt_bf16<<<dim3(1280), blk, 0, stream>>>(inw, inwb, 2097152);
    cvt_bf16<<<dim3(1280), blk, 0, stream>>>(xw,  xwb,  81920);
    cvt_bf16<<<dim3(1280), blk, 0, stream>>>(dtw, dtwb, 65536);

    // in_proj (fused x+gate): [2048 x 8192] = hsb @ inwb^T, dual bf16 epilogue
    gemm_bf16_bt<<<dim3(64, 16, 1), blk, 0, stream>>>(
        hsb, D_MODEL, inwb, D_MODEL, xraw, D_INNER, pg, nullptr,
        M_TOK, 2 * D_INNER, D_MODEL, 5, 0);

    // ow conversion (inwb dead; owb = front of its region)
    cvt_bf16<<<dim3(1280), blk, 0, stream>>>(ow, owb, 1048576);

    // conv + SiLU: xraw -> xtb
    conv_silu_k<<<dim3(16, M_TOK), blk, 0, stream>>>(xraw, cw, cb, xtb);

    // x_proj split-K x8: part[z] = xtb @ xwb^T (K slice)
    gemm_bf16_bt<<<dim3(2, 16, 8), blk, 0, stream>>>(
        xtb, D_INNER, xwb, D_INNER, part, 160, nullptr, nullptr,
        M_TOK, 160, D_INNER, 0, (size_t)M_TOK * 160);
    reduce_ssm<<<dim3(1280), blk, 0, stream>>>(part, ssmf, ssmb);

    // dt_proj + softplus(+bias) -> dtb16 (bf16; part dead)
    gemm_bf16_bt<<<dim3(32, 16, 1), blk, 0, stream>>>(
        ssmb, 160, dtwb, DT_RANK, dtb16, D_INNER, nullptr, dtb,
        M_TOK, D_INNER, DT_RANK, 1, 0);

    // chunked selective scan (+ D-skip + gate), y bf16 over xtb
    scan_pass1<<<dim3(16, NCHUNK, B_SZ), blk, 0, stream>>>(dtb16, xtb, ssmf, Ap, Pc, Qc);
    scan_pass2<<<dim3((B_SZ * D_INNER * D_STATE) / 256), blk, 0, stream>>>(Pc, Qc);
    scan_pass3<<<dim3(16, NCHUNK, B_SZ), blk, 0, stream>>>(dtb16, xtb, pg, ssmf, Ap, Qc, Dp);

    // out_proj split-K x2: opart (pg+xraw region dead) -> reduce -> out
    gemm_bf16_bt<<<dim3(16, 16, 2), blk, 0, stream>>>(
        xtb, D_INNER, owb, D_INNER, opart, D_MODEL, nullptr, nullptr,
        M_TOK, D_MODEL, D_INNER, 0, (size_t)M_TOK * D_MODEL);
    reduce_out<<<dim3(1024), blk, 0, stream>>>(opart, out, (M_TOK * D_MODEL) / 4);
}

// Round 8
// 324.089 us; speedup vs baseline: 1.2135x; 1.2135x over previous
//
#include <hip/hip_runtime.h>
#include <hip/hip_bf16.h>
#include <math.h>

#define B_SZ    2
#define LSEQ    1024
#define D_MODEL 2048
#define D_INNER 4096
#define D_STATE 16
#define DT_RANK 128
#define M_TOK   (B_SZ * LSEQ)      // 2048 token rows
#define NCHUNK  16
#define LCHUNK  (LSEQ / NCHUNK)    // 64

typedef __attribute__((ext_vector_type(8))) short bf16x8;
typedef __attribute__((ext_vector_type(4))) float f32x4;

__device__ __forceinline__ float softplusf_(float x) {
    return fmaxf(x, 0.f) + log1pf(expf(-fabsf(x)));
}
__device__ __forceinline__ unsigned f2bf(float f) {
    union { float f; unsigned u; } v; v.f = f;
    const unsigned u = v.u;
    return (u + 0x7fffu + ((u >> 16) & 1u)) >> 16;   // RNE, finite inputs
}
__device__ __forceinline__ float bf2f(unsigned u) {
    union { unsigned u; float f; } v; v.u = u << 16; return v.f;
}
__device__ __forceinline__ void gload16(const void* g, void* lds) {
    __builtin_amdgcn_global_load_lds(
        (const __attribute__((address_space(1))) void*)g,
        (__attribute__((address_space(3))) void*)lds, 16, 0, 0);
}

// ---------------------------------------------------------------------------
// bf16 MFMA GEMM: C[M,N] = A[M,K](bf16) * B[N,K](bf16)^T, fp32 acc.
// 128x128 tile, BK=64, 512 thr = 8 waves (2x4, wave tile 64x32). Double-
// buffered LDS (64 KB -> 2 blocks/CU -> 4 waves/SIMD) with counted vmcnt(4):
// iter kt stages tile kt+1 (4 loads/wave) then waits vmcnt(4) = tile kt done,
// next tile's loads stay in flight across both barriers.
// Race ledger: STAGE into buf[b] is issued only after the trailing s_barrier
// of the iteration that read buf[b]; vmcnt retires in issue order (m135);
// sched_barrier(0) after each s_barrier fences compiler motion (rule #18).
// LDS: rows of 8 16B-chunks; read phys chunk = ch ^ (row&7) -> 32-bank
// balanced (conflict-free); staging SOURCE pre-swizzled with the same
// involution, linear wave-uniform dest (both-sides rule m104/m231).
// NO XCD swizzle: natural bx-fastest order already binds B-panels to XCD L2
// (round-7 swizzle tripled FETCH_SIZE -> reverted).
// Split-K via gridDim.z (C += z*zstride).
// epi: 0 = f32 store; 1 = softplus(v+bias[col]) -> bf16; 5 = dual bf16
// (col<4096 -> Cv bf16 ld 4096, col>=4096 -> Cv2 bf16 ld 4096).
// ---------------------------------------------------------------------------
__global__ __launch_bounds__(512, 4)
void gemm_bf16_bt(const ushort* __restrict__ A, int lda,
                  const ushort* __restrict__ B, int ldb,
                  void* __restrict__ Cv, int ldc,
                  void* __restrict__ Cv2,
                  const float* __restrict__ bias,
                  int M, int N, int K, int epi, size_t zstride)
{
    __shared__ ushort As[2][128 * 64];
    __shared__ ushort Bs[2][128 * 64];
    const int t    = threadIdx.x;
    const int bm   = blockIdx.y << 7, bn = blockIdx.x << 7;
    const int wave = t >> 6, lane = t & 63;
    const int wr   = (wave >> 2) << 6;     // 0 / 64
    const int wc   = (wave & 3) << 5;      // 0 / 32 / 64 / 96
    const int lr   = lane & 15, lh = lane >> 4;
    const int kper  = K / gridDim.z;
    const int kbase = blockIdx.z * kper;
    const int nkt   = kper >> 6;           // BK=64

    // staging: seg = wave + it*8 (16 segs x 64 chunks per operand);
    // chunk c = seg*64 + lane; row = c>>3 = seg*8 + (lane>>3); j = lane&7;
    // source column chunk jj = j ^ (row&7) = (lane&7) ^ ((lane>>3)&7)
    const ushort* ga[2]; const ushort* gb[2];
    int ldof[2];
#pragma unroll
    for (int it = 0; it < 2; ++it) {
        const int seg = wave + (it << 3);
        const int row = (seg << 3) + (lane >> 3);
        const int jj  = (lane & 7) ^ ((lane >> 3) & 7);
        ga[it] = A + (size_t)(bm + row) * lda + kbase + jj * 8;
        int gn = bn + row; gn = gn < N ? gn : N - 1;
        gb[it] = B + (size_t)gn * ldb + kbase + jj * 8;
        ldof[it] = seg << 9;               // ushort offset: seg*512
    }

#define STAGE(bsel) do {                                                \
    _Pragma("unroll")                                                   \
    for (int it = 0; it < 2; ++it) {                                    \
        gload16(ga[it], &As[bsel][ldof[it]]);                           \
        gload16(gb[it], &Bs[bsel][ldof[it]]);                           \
        ga[it] += 64; gb[it] += 64;                                     \
    }                                                                   \
} while (0)

    f32x4 acc[4][2];
#pragma unroll
    for (int i = 0; i < 4; ++i)
#pragma unroll
        for (int j = 0; j < 2; ++j) {
            acc[i][j][0] = 0.f; acc[i][j][1] = 0.f;
            acc[i][j][2] = 0.f; acc[i][j][3] = 0.f;
        }

    STAGE(0);
    for (int kt = 0; kt < nkt; ++kt) {
        const int cur = kt & 1;
        if (kt + 1 < nkt) {
            STAGE(cur ^ 1);
            asm volatile("s_waitcnt vmcnt(4)" ::: "memory");   // tile kt done
        } else {
            asm volatile("s_waitcnt vmcnt(0)" ::: "memory");
        }
        __builtin_amdgcn_s_barrier();       // tile kt staged by all waves
        __builtin_amdgcn_sched_barrier(0);

        const char* Ab = (const char*)As[cur];
        const char* Bb = (const char*)Bs[cur];
#pragma unroll
        for (int kk = 0; kk < 2; ++kk) {
            bf16x8 af[4], bf[2];
#pragma unroll
            for (int mi = 0; mi < 4; ++mi) {
                const int row = wr + (mi << 4) + lr;
                const int ch  = ((kk << 2) + lh) ^ (row & 7);
                af[mi] = *(const bf16x8*)(Ab + row * 128 + (ch << 4));
            }
#pragma unroll
            for (int nj = 0; nj < 2; ++nj) {
                const int row = wc + (nj << 4) + lr;
                const int ch  = ((kk << 2) + lh) ^ (row & 7);
                bf[nj] = *(const bf16x8*)(Bb + row * 128 + (ch << 4));
            }
#pragma unroll
            for (int mi = 0; mi < 4; ++mi)
#pragma unroll
                for (int nj = 0; nj < 2; ++nj)
                    acc[mi][nj] = __builtin_amdgcn_mfma_f32_16x16x32_bf16(
                        af[mi], bf[nj], acc[mi][nj], 0, 0, 0);
        }
        __builtin_amdgcn_s_barrier();       // all waves done reading buf[cur]
        __builtin_amdgcn_sched_barrier(0);
    }
#undef STAGE

    float*  C  = (float*)Cv + (size_t)blockIdx.z * zstride;
    ushort* Cb = (ushort*)Cv;
    ushort* C2 = (ushort*)Cv2;
#pragma unroll
    for (int mi = 0; mi < 4; ++mi) {
#pragma unroll
        for (int nj = 0; nj < 2; ++nj) {
            const int col  = bn + wc + (nj << 4) + lr;
            const int row0 = bm + wr + (mi << 4) + (lh << 2);
            if (col < N) {
#pragma unroll
                for (int r = 0; r < 4; ++r) {
                    const float v = acc[mi][nj][r];
                    if (epi == 0) {
                        C[(size_t)(row0 + r) * ldc + col] = v;
                    } else if (epi == 1) {
                        Cb[(size_t)(row0 + r) * ldc + col] =
                            (ushort)f2bf(softplusf_(v + bias[col]));
                    } else {  // epi == 5: dual bf16 store (fused in_proj)
                        if (col < D_INNER)
                            Cb[(size_t)(row0 + r) * ldc + col] = (ushort)f2bf(v);
                        else
                            C2[(size_t)(row0 + r) * ldc + (col - D_INNER)] = (ushort)f2bf(v);
                    }
                }
            }
        }
    }
}

// ---------------------------------------------------------------------------
__global__ __launch_bounds__(256)
void cvt_bf16(const float* __restrict__ in, ushort* __restrict__ out, int n8)
{
    for (int i = blockIdx.x * 256 + threadIdx.x; i < n8; i += gridDim.x * 256) {
        const float4 v0 = ((const float4*)in)[i * 2];
        const float4 v1 = ((const float4*)in)[i * 2 + 1];
        int4 p;
        p.x = (int)(f2bf(v0.x) | (f2bf(v0.y) << 16));
        p.y = (int)(f2bf(v0.z) | (f2bf(v0.w) << 16));
        p.z = (int)(f2bf(v1.x) | (f2bf(v1.y) << 16));
        p.w = (int)(f2bf(v1.z) | (f2bf(v1.w) << 16));
        ((int4*)out)[i] = p;
    }
}

// ---------------------------------------------------------------------------
__global__ __launch_bounds__(256)
void reduce_out(const float* __restrict__ part, float* __restrict__ out, int n4)
{
    for (int i = blockIdx.x * 256 + threadIdx.x; i < n4; i += gridDim.x * 256) {
        const float4 a = ((const float4*)part)[i];
        const float4 b = ((const float4*)(part + (size_t)M_TOK * D_MODEL))[i];
        ((float4*)out)[i] = make_float4(a.x + b.x, a.y + b.y, a.z + b.z, a.w + b.w);
    }
}

// ---------------------------------------------------------------------------
// Depthwise causal conv (K=4) + bias + SiLU, m-chunked with register window.
// Each thread: one d, 64 consecutive m within one batch. x read once.
// ---------------------------------------------------------------------------
__global__ __launch_bounds__(256)
void conv_silu_k(const ushort* __restrict__ xraw,
                 const float* __restrict__ cw,
                 const float* __restrict__ cb,
                 ushort* __restrict__ xb)
{
    const int d  = (blockIdx.x << 8) + threadIdx.x;   // 0..4095
    const int m0 = blockIdx.y << 6;                   // chunk base (64 | 1024)
    const int l0 = m0 & (LSEQ - 1);
    const float4 w = *(const float4*)&cw[d << 2];
    const float bias = cb[d];
    float x3 = 0.f, x2 = 0.f, x1 = 0.f;
    if (l0 > 0) {   // previous 3 tokens exist (l0 >= 64)
        x3 = bf2f(xraw[(size_t)(m0 - 3) * D_INNER + d]);
        x2 = bf2f(xraw[(size_t)(m0 - 2) * D_INNER + d]);
        x1 = bf2f(xraw[(size_t)(m0 - 1) * D_INNER + d]);
    }
#pragma unroll 4
    for (int i = 0; i < 64; ++i) {
        const size_t m = (size_t)m0 + i;
        const float x0 = bf2f(xraw[m * D_INNER + d]);
        float acc = bias;
        acc = fmaf(w.x, x3, acc);
        acc = fmaf(w.y, x2, acc);
        acc = fmaf(w.z, x1, acc);
        acc = fmaf(w.w, x0, acc);
        const float sg = 1.f / (1.f + expf(-acc));
        xb[m * D_INNER + d] = (ushort)f2bf(acc * sg);
        x3 = x2; x2 = x1; x1 = x0;
    }
}

// ---------------------------------------------------------------------------
__global__ __launch_bounds__(256)
void reduce_ssm(const float* __restrict__ part,
                float* __restrict__ ssmf, ushort* __restrict__ ssmb)
{
    const int i = blockIdx.x * 256 + threadIdx.x;   // < 2048*160
    float v = 0.f;
#pragma unroll
    for (int z = 0; z < 8; ++z) v += part[(size_t)z * (M_TOK * 160) + i];
    ssmf[i] = v;
    ssmb[i] = (ushort)f2bf(v);
}

// ---------------------------------------------------------------------------
// Chunked selective scan: thread owns (b, d, chunk), 16 states in VGPRs.
// ---------------------------------------------------------------------------
__global__ __launch_bounds__(256)
void scan_pass1(const ushort* __restrict__ dtp,   // dt bf16 [M][4096]
                const ushort* __restrict__ xb,    // x bf16 [M][4096]
                const float* __restrict__ ssm,    // [M][160], B @ 128+s
                const float* __restrict__ Ap,     // [4096][16]
                float* __restrict__ Pc, float* __restrict__ Qc)
{
    const int d = (blockIdx.x << 8) + threadIdx.x;
    const int c = blockIdx.y, b = blockIdx.z;
    float a[16];
    *(float4*)&a[0]  = *(const float4*)&Ap[d * 16];
    *(float4*)&a[4]  = *(const float4*)&Ap[d * 16 + 4];
    *(float4*)&a[8]  = *(const float4*)&Ap[d * 16 + 8];
    *(float4*)&a[12] = *(const float4*)&Ap[d * 16 + 12];
    float q[16];
#pragma unroll
    for (int s = 0; s < 16; ++s) q[s] = 0.f;
    float dtsum = 0.f;
    const size_t m0 = (size_t)b * LSEQ + (size_t)c * LCHUNK;
#pragma unroll 2
    for (int l = 0; l < LCHUNK; ++l) {
        const size_t m = m0 + l;
        const float dt = bf2f(dtp[m * D_INNER + d]);
        const float xv = bf2f(xb[m * D_INNER + d]);
        const float4 B0 = *(const float4*)&ssm[m * 160 + 128];
        const float4 B1 = *(const float4*)&ssm[m * 160 + 132];
        const float4 B2 = *(const float4*)&ssm[m * 160 + 136];
        const float4 B3 = *(const float4*)&ssm[m * 160 + 140];
        const float Bv[16] = {B0.x,B0.y,B0.z,B0.w, B1.x,B1.y,B1.z,B1.w,
                              B2.x,B2.y,B2.z,B2.w, B3.x,B3.y,B3.z,B3.w};
        const float t1 = dt * xv;
#pragma unroll
        for (int s = 0; s < 16; ++s) {
            const float dA = __expf(dt * a[s]);
            q[s] = fmaf(q[s], dA, t1 * Bv[s]);
        }
        dtsum += dt;
    }
    const size_t o = (((size_t)b * D_INNER + d) * NCHUNK + c) * D_STATE;
    float P[16];
#pragma unroll
    for (int s = 0; s < 16; ++s) P[s] = __expf(a[s] * dtsum);
#pragma unroll
    for (int s4 = 0; s4 < 4; ++s4) {
        *(float4*)&Pc[o + s4 * 4] = make_float4(P[s4*4], P[s4*4+1], P[s4*4+2], P[s4*4+3]);
        *(float4*)&Qc[o + s4 * 4] = make_float4(q[s4*4], q[s4*4+1], q[s4*4+2], q[s4*4+3]);
    }
}

__global__ __launch_bounds__(256)
void scan_pass2(const float* __restrict__ Pc, float* __restrict__ Qc)
{
    const int i = blockIdx.x * 256 + threadIdx.x;   // (b*4096+d)*16+s
    const size_t base = (size_t)(i >> 4) * (NCHUNK * D_STATE) + (i & 15);
    float st = 0.f;
#pragma unroll
    for (int c = 0; c < NCHUNK; ++c) {
        const float P = Pc[base + c * D_STATE];
        const float q = Qc[base + c * D_STATE];
        Qc[base + c * D_STATE] = st;    // state entering chunk c
        st = fmaf(st, P, q);
    }
}

__global__ __launch_bounds__(256)
void scan_pass3(const ushort* __restrict__ dtp,   // dt bf16
                ushort* __restrict__ xb,          // x bf16 in / y bf16 out
                const ushort* __restrict__ gb,    // gate bf16
                const float* __restrict__ ssm,
                const float* __restrict__ Ap,
                const float* __restrict__ Qc,
                const float* __restrict__ Dp)
{
    const int d = (blockIdx.x << 8) + threadIdx.x;
    const int c = blockIdx.y, b = blockIdx.z;
    float a[16], st[16];
    *(float4*)&a[0]  = *(const float4*)&Ap[d * 16];
    *(float4*)&a[4]  = *(const float4*)&Ap[d * 16 + 4];
    *(float4*)&a[8]  = *(const float4*)&Ap[d * 16 + 8];
    *(float4*)&a[12] = *(const float4*)&Ap[d * 16 + 12];
    const size_t qo = (((size_t)b * D_INNER + d) * NCHUNK + c) * D_STATE;
    *(float4*)&st[0]  = *(const float4*)&Qc[qo];
    *(float4*)&st[4]  = *(const float4*)&Qc[qo + 4];
    *(float4*)&st[8]  = *(const float4*)&Qc[qo + 8];
    *(float4*)&st[12] = *(const float4*)&Qc[qo + 12];
    const float Dd = Dp[d];
    const size_t m0 = (size_t)b * LSEQ + (size_t)c * LCHUNK;
#pragma unroll 2
    for (int l = 0; l < LCHUNK; ++l) {
        const size_t m = m0 + l;
        const float dt = bf2f(dtp[m * D_INNER + d]);
        const float xv = bf2f(xb[m * D_INNER + d]);
        const float gv = bf2f(gb[m * D_INNER + d]);
        const float4 B0 = *(const float4*)&ssm[m * 160 + 128];
        const float4 B1 = *(const float4*)&ssm[m * 160 + 132];
        const float4 B2 = *(const float4*)&ssm[m * 160 + 136];
        const float4 B3 = *(const float4*)&ssm[m * 160 + 140];
        const float4 C0 = *(const float4*)&ssm[m * 160 + 144];
        const float4 C1 = *(const float4*)&ssm[m * 160 + 148];
        const float4 C2 = *(const float4*)&ssm[m * 160 + 152];
        const float4 C3 = *(const float4*)&ssm[m * 160 + 156];
        const float Bv[16] = {B0.x,B0.y,B0.z,B0.w, B1.x,B1.y,B1.z,B1.w,
                              B2.x,B2.y,B2.z,B2.w, B3.x,B3.y,B3.z,B3.w};
        const float Cv[16] = {C0.x,C0.y,C0.z,C0.w, C1.x,C1.y,C1.z,C1.w,
                              C2.x,C2.y,C2.z,C2.w, C3.x,C3.y,C3.z,C3.w};
        const float t1 = dt * xv;
        float y = 0.f;
#pragma unroll
        for (int s = 0; s < 16; ++s) {
            const float dA = __expf(dt * a[s]);
            st[s] = fmaf(st[s], dA, t1 * Bv[s]);
            y = fmaf(st[s], Cv[s], y);
        }
        const float yg  = fmaf(Dd, xv, y);
        const float sig = 1.f / (1.f + expf(-gv));
        xb[m * D_INNER + d] = (ushort)f2bf(yg * (gv * sig));
    }
}

// ---------------------------------------------------------------------------
extern "C" void kernel_launch(void* const* d_in, const int* in_sizes, int n_in,
                              void* d_out, int out_size, void* d_ws, size_t ws_size,
                              hipStream_t stream)
{
    (void)in_sizes; (void)n_in; (void)out_size; (void)ws_size;
    const float* hs  = (const float*)d_in[0];  // [2048,2048]
    const float* inw = (const float*)d_in[1];  // [8192,2048]
    const float* cw  = (const float*)d_in[2];  // [4096,4]
    const float* cb  = (const float*)d_in[3];  // [4096]
    const float* xw  = (const float*)d_in[4];  // [160,4096]
    const float* dtw = (const float*)d_in[5];  // [4096,128]
    const float* dtb = (const float*)d_in[6];  // [4096]
    const float* Ap  = (const float*)d_in[7];  // [4096,16]
    const float* Dp  = (const float*)d_in[8];  // [4096]
    const float* ow  = (const float*)d_in[9];  // [2048,4096]
    float* out = (float*)d_out;                // [2048,2048]

    // ------------------------------------------------------------------
    // Workspace layout, f32-offset units (bf16 sizes are f32-EQUIV =
    // ushort_count/2). Total 24,150,016 f32 = 96.6 MB. Identical to the
    // PROVEN round-6 layout (single-writer-before-reader on the timeline).
    // ------------------------------------------------------------------
    float*  ws    = (float*)d_ws;
    ushort* pg    = (ushort*)(ws + 0);          // gate bf16 [2048][4096]
    ushort* xraw  = (ushort*)(ws + 4194304);    // x bf16 pre-conv
    ushort* xtb   = (ushort*)(ws + 8388608);    // xt bf16 -> y bf16
    float*  ssmf  = ws + 12582912;              // f32 [2048][160]
    ushort* ssmb  = (ushort*)(ws + 12910592);   // bf16 [2048][160]
    ushort* xwb   = (ushort*)(ws + 13074432);   // bf16 [160][4096]
    ushort* dtwb  = (ushort*)(ws + 13402112);   // bf16 [4096][128]
    ushort* hsb   = (ushort*)(ws + 13664256);   // bf16 [2048][2048]
    ushort* inwb  = (ushort*)(ws + 15761408);   // bf16 [8192][2048]
    ushort* owb   = (ushort*)(ws + 15761408);   // alias: after in_proj
    float*  part  = ws + 19955712;              // x_proj partials, dead by dt_proj
    ushort* dtb16 = (ushort*)(ws + 19955712);   // alias: after reduce_ssm
    float*  Pc    = ws + 4194304;               // alias: after conv (xraw dead)
    float*  Qc    = ws + 6291456;
    float*  opart = ws + 0;                     // alias: after scan_pass3

    const dim3 blk(256);
    const dim3 blk512(512);

    // conversions
    cvt_bf16<<<dim3(1280), blk, 0, stream>>>(hs,  hsb,  524288);
    cvt_bf16<<<dim3(1280), blk, 0, stream>>>(inw, inwb, 2097152);
    cvt_bf16<<<dim3(1280), blk, 0, stream>>>(xw,  xwb,  81920);
    cvt_bf16<<<dim3(1280), blk, 0, stream>>>(dtw, dtwb, 65536);

    // in_proj (fused x+gate): [2048 x 8192] = hsb @ inwb^T, dual bf16 epilogue
    gemm_bf16_bt<<<dim3(64, 16, 1), blk512, 0, stream>>>(
        hsb, D_MODEL, inwb, D_MODEL, xraw, D_INNER, pg, nullptr,
        M_TOK, 2 * D_INNER, D_MODEL, 5, 0);

    // ow conversion (inwb dead; owb = front of its region)
    cvt_bf16<<<dim3(1280), blk, 0, stream>>>(ow, owb, 1048576);

    // conv + SiLU: xraw -> xtb  (m-chunked, x read once)
    conv_silu_k<<<dim3(16, 32), blk, 0, stream>>>(xraw, cw, cb, xtb);

    // x_proj split-K x8: part[z] = xtb @ xwb^T (K slice)
    gemm_bf16_bt<<<dim3(2, 16, 8), blk512, 0, stream>>>(
        xtb, D_INNER, xwb, D_INNER, part, 160, nullptr, nullptr,
        M_TOK, 160, D_INNER, 0, (size_t)M_TOK * 160);
    reduce_ssm<<<dim3(1280), blk, 0, stream>>>(part, ssmf, ssmb);

    // dt_proj + softplus(+bias) -> dtb16 (bf16; part dead)
    gemm_bf16_bt<<<dim3(32, 16, 1), blk512, 0, stream>>>(
        ssmb, 160, dtwb, DT_RANK, dtb16, D_INNER, nullptr, dtb,
        M_TOK, D_INNER, DT_RANK, 1, 0);

    // chunked selective scan (+ D-skip + gate), y bf16 over xtb
    scan_pass1<<<dim3(16, NCHUNK, B_SZ), blk, 0, stream>>>(dtb16, xtb, ssmf, Ap, Pc, Qc);
    scan_pass2<<<dim3((B_SZ * D_INNER * D_STATE) / 256), blk, 0, stream>>>(Pc, Qc);
    scan_pass3<<<dim3(16, NCHUNK, B_SZ), blk, 0, stream>>>(dtb16, xtb, pg, ssmf, Ap, Qc, Dp);

    // out_proj split-K x2: opart (pg+xraw region dead) -> reduce -> out
    gemm_bf16_bt<<<dim3(16, 16, 2), blk512, 0, stream>>>(
        xtb, D_INNER, owb, D_INNER, opart, D_MODEL, nullptr, nullptr,
        M_TOK, D_MODEL, D_INNER, 0, (size_t)M_TOK * D_MODEL);
    reduce_out<<<dim3(1024), blk, 0, stream>>>(opart, out, (M_TOK * D_MODEL) / 4);
}

// Round 10
// 307.337 us; speedup vs baseline: 1.2796x; 1.0545x over previous
//
#include <hip/hip_runtime.h>
#include <hip/hip_bf16.h>
#include <math.h>

#define B_SZ    2
#define LSEQ    1024
#define D_MODEL 2048
#define D_INNER 4096
#define D_STATE 16
#define DT_RANK 128
#define M_TOK   (B_SZ * LSEQ)      // 2048 token rows
#define NCHUNK  16
#define LCHUNK  (LSEQ / NCHUNK)    // 64

typedef __attribute__((ext_vector_type(8))) short bf16x8;
typedef __attribute__((ext_vector_type(4))) float f32x4;

__device__ __forceinline__ float softplusf_(float x) {
    return fmaxf(x, 0.f) + log1pf(expf(-fabsf(x)));
}
__device__ __forceinline__ unsigned f2bf(float f) {
    union { float f; unsigned u; } v; v.f = f;
    const unsigned u = v.u;
    return (u + 0x7fffu + ((u >> 16) & 1u)) >> 16;   // RNE, finite inputs
}
__device__ __forceinline__ float bf2f(unsigned u) {
    union { unsigned u; float f; } v; v.u = u << 16; return v.f;
}
__device__ __forceinline__ void gload16(const void* g, void* lds) {
    __builtin_amdgcn_global_load_lds(
        (const __attribute__((address_space(1))) void*)g,
        (__attribute__((address_space(3))) void*)lds, 16, 0, 0);
}

// ===========================================================================
// 8-phase 256x256 bf16 MFMA GEMM (plain-HIP port of the m201 template).
// C[M,N] = A[M,K] * B[N,K]^T, fp32 acc. 512 thr = 8 waves (2M x 4N), BK=64.
// LDS 128 KiB: [dbuf][op A/B][half 128x64]. Per K-tile: 4 phases = 4 block
// quadrants (A-half x B-half); per phase: {ds_read slice, stage 1 half-tile
// (2 gload_lds), barrier, lgkmcnt(0)+sched_barrier, setprio(1), 16 MFMA,
// setprio(0), barrier}. Counted vmcnt(6) at tile boundaries only (3 halves
// in flight); vmcnt(0) entering the last tile.
// Stage schedule per tile t: p0->(t+1)A1, p1->(t+2)A0, p2->(t+2)B0,
// p3->(t+2)B1. Slot-reuse ledger: a slot's last ds_read (p_r) precedes the
// overwriting stage (p_s > p_r) across a barrier; A-slices held in af regs
// across 2 phases, B0 held in bf0 through p3 (no re-reads -> min 24 KB/tile).
// Landing ledger: entering tile t, vmcnt(6) leaves only (t+1)A0,B0,B1 in
// flight -> all 4 halves of tile t landed.
// Swizzle (both sides, r3-r8 verified 0 conflicts): src chunk jj = j^(row&7),
// linear LDS dest; ds_read chunk ch^(row&7).
// epi: 0 = f32 (+ z*zstride, split-K); 5 = dual bf16 (col<4096 -> Cv,
// else Cv2 at col-4096, both ld = ldc).
// ===========================================================================
__global__ __launch_bounds__(512, 2)
void gemm256_8ph(const ushort* __restrict__ A, int lda,
                 const ushort* __restrict__ B, int ldb,
                 void* __restrict__ Cv, int ldc,
                 void* __restrict__ Cv2,
                 int K, int epi, size_t zstride)
{
    __shared__ ushort Lds[2][2][2][128 * 64];   // [dbuf][A/B][half][...]
    const int t    = threadIdx.x;
    const int bm   = blockIdx.y << 8, bn = blockIdx.x << 8;
    const int wave = t >> 6, lane = t & 63;
    const int wm   = wave >> 2;          // 0..1  (64-row slice within half)
    const int wn   = wave & 3;           // 0..3  (32-col slice within half)
    const int lr   = lane & 15, lh = lane >> 4;
    const int kper  = K / gridDim.z;
    const int kbase = blockIdx.z * kper;
    const int nkt   = kper >> 6;

    // staging: issue it in {0,1}: flat = t + it*512; row = flat>>3; j = flat&7
    const ushort* gsA[2]; const ushort* gsB[2];
    int dof[2];
#pragma unroll
    for (int it = 0; it < 2; ++it) {
        const int flat = t + (it << 9);
        const int row  = flat >> 3, j = flat & 7;
        const int jj   = j ^ (row & 7);
        gsA[it] = A + (size_t)(bm + row) * lda + kbase + jj * 8;
        gsB[it] = B + (size_t)(bn + row) * ldb + kbase + jj * 8;
        dof[it] = flat << 3;             // ushort offset (16 B per chunk)
    }

#define STG_A(half, kt, db) do {                                            \
    _Pragma("unroll")                                                       \
    for (int it = 0; it < 2; ++it)                                          \
        gload16(gsA[it] + (size_t)((half) * 128) * lda + (kt) * 64,         \
                &Lds[db][0][half][dof[it]]);                                \
} while (0)
#define STG_B(half, kt, db) do {                                            \
    _Pragma("unroll")                                                       \
    for (int it = 0; it < 2; ++it)                                          \
        gload16(gsB[it] + (size_t)((half) * 128) * ldb + (kt) * 64,         \
                &Lds[db][1][half][dof[it]]);                                \
} while (0)
#define RD_A(db, half) do {                                                 \
    _Pragma("unroll")                                                       \
    for (int mi = 0; mi < 4; ++mi)                                          \
    _Pragma("unroll")                                                       \
    for (int kk = 0; kk < 2; ++kk) {                                        \
        const int row_ = wm * 64 + mi * 16 + lr;                            \
        const int ch_  = ((kk << 2) + lh) ^ (row_ & 7);                     \
        af[mi * 2 + kk] = *(const bf16x8*)((const char*)Lds[db][0][half]    \
                             + row_ * 128 + (ch_ << 4));                    \
    }                                                                       \
} while (0)
#define RD_B(db, half, dst) do {                                            \
    _Pragma("unroll")                                                       \
    for (int nj = 0; nj < 2; ++nj)                                          \
    _Pragma("unroll")                                                       \
    for (int kk = 0; kk < 2; ++kk) {                                        \
        const int row_ = wn * 32 + nj * 16 + lr;                            \
        const int ch_  = ((kk << 2) + lh) ^ (row_ & 7);                     \
        dst[nj * 2 + kk] = *(const bf16x8*)((const char*)Lds[db][1][half]   \
                             + row_ * 128 + (ch_ << 4));                    \
    }                                                                       \
} while (0)
#define MFMA_Q(q, bfx) do {                                                 \
    _Pragma("unroll")                                                       \
    for (int mi = 0; mi < 4; ++mi)                                          \
    _Pragma("unroll")                                                       \
    for (int nj = 0; nj < 2; ++nj)                                          \
    _Pragma("unroll")                                                       \
    for (int kk = 0; kk < 2; ++kk)                                          \
        acc[q][mi][nj] = __builtin_amdgcn_mfma_f32_16x16x32_bf16(           \
            af[mi * 2 + kk], bfx[nj * 2 + kk], acc[q][mi][nj], 0, 0, 0);    \
} while (0)
#define PH_PRE()  __builtin_amdgcn_s_barrier();                             \
                  asm volatile("s_waitcnt lgkmcnt(0)" ::: "memory");        \
                  __builtin_amdgcn_sched_barrier(0);                        \
                  __builtin_amdgcn_s_setprio(1)
#define PH_POST() __builtin_amdgcn_s_setprio(0);                            \
                  __builtin_amdgcn_s_barrier();                             \
                  __builtin_amdgcn_sched_barrier(0)

    f32x4 acc[4][4][2];
#pragma unroll
    for (int q = 0; q < 4; ++q)
#pragma unroll
        for (int i = 0; i < 4; ++i)
#pragma unroll
            for (int j = 0; j < 2; ++j) {
                acc[q][i][j][0] = 0.f; acc[q][i][j][1] = 0.f;
                acc[q][i][j][2] = 0.f; acc[q][i][j][3] = 0.f;
            }

    bf16x8 af[8], bf0[4], bf1[4];

    // prologue: tile0 {A0,B0,B1,A1} + tile1 {A0,B0,B1}; tile0 fully landed
    STG_A(0, 0, 0); STG_B(0, 0, 0); STG_B(1, 0, 0); STG_A(1, 0, 0);
    if (nkt > 1) { STG_A(0, 1, 1); STG_B(0, 1, 1); STG_B(1, 1, 1); }
    asm volatile("s_waitcnt vmcnt(6)" ::: "memory");
    __builtin_amdgcn_s_barrier();
    __builtin_amdgcn_sched_barrier(0);

    for (int kt = 0; kt < nkt; ++kt) {
        const int db = kt & 1;
        // ---- phase 0: quadrant (A0,B0); stage (kt+1)A1 -> db^1
        RD_A(db, 0); RD_B(db, 0, bf0);
        if (kt + 1 < nkt) STG_A(1, kt + 1, db ^ 1);
        PH_PRE();
        MFMA_Q(0, bf0);
        PH_POST();
        // ---- phase 1: quadrant (A0,B1); stage (kt+2)A0 -> db
        RD_B(db, 1, bf1);
        if (kt + 2 < nkt) STG_A(0, kt + 2, db);
        PH_PRE();
        MFMA_Q(1, bf1);
        PH_POST();
        // ---- phase 2: quadrant (A1,B1); stage (kt+2)B0 -> db
        RD_A(db, 1);
        if (kt + 2 < nkt) STG_B(0, kt + 2, db);
        PH_PRE();
        MFMA_Q(2, bf1);
        PH_POST();
        // ---- phase 3: quadrant (A1,B0), no reads; stage (kt+2)B1 -> db
        if (kt + 2 < nkt) STG_B(1, kt + 2, db);
        PH_PRE();
        MFMA_Q(3, bf0);
        __builtin_amdgcn_s_setprio(0);
        if (kt + 2 >= nkt) {
            asm volatile("s_waitcnt vmcnt(0)" ::: "memory");
        } else {
            asm volatile("s_waitcnt vmcnt(6)" ::: "memory");
        }
        __builtin_amdgcn_s_barrier();
        __builtin_amdgcn_sched_barrier(0);
    }
#undef STG_A
#undef STG_B
#undef RD_A
#undef RD_B
#undef MFMA_Q
#undef PH_PRE
#undef PH_POST

    float*  C  = (float*)Cv + (size_t)blockIdx.z * zstride;
    ushort* Cb = (ushort*)Cv;
    ushort* C2 = (ushort*)Cv2;
#pragma unroll
    for (int q = 0; q < 4; ++q) {
        const int mh = q >> 1;                        // 0,0,1,1
        const int nh = (q == 1 || q == 2) ? 1 : 0;    // 0,1,1,0
#pragma unroll
        for (int mi = 0; mi < 4; ++mi) {
#pragma unroll
            for (int nj = 0; nj < 2; ++nj) {
                const int col  = bn + nh * 128 + wn * 32 + nj * 16 + lr;
                const int row0 = bm + mh * 128 + wm * 64 + mi * 16 + (lh << 2);
#pragma unroll
                for (int r = 0; r < 4; ++r) {
                    const float v = acc[q][mi][nj][r];
                    if (epi == 0) {
                        C[(size_t)(row0 + r) * ldc + col] = v;
                    } else {  // epi == 5: dual bf16 (fused in_proj)
                        if (col < D_INNER)
                            Cb[(size_t)(row0 + r) * ldc + col] = (ushort)f2bf(v);
                        else
                            C2[(size_t)(row0 + r) * ldc + (col - D_INNER)] = (ushort)f2bf(v);
                    }
                }
            }
        }
    }
}

// ---------------------------------------------------------------------------
// r8 128x128 dbuf GEMM (kept for the skinny x_proj / dt_proj shapes).
// epi: 0 = f32 store (split-K via z*zstride); 1 = softplus(v+bias) -> bf16.
// ---------------------------------------------------------------------------
__global__ __launch_bounds__(512, 4)
void gemm_bf16_bt(const ushort* __restrict__ A, int lda,
                  const ushort* __restrict__ B, int ldb,
                  void* __restrict__ Cv, int ldc,
                  const float* __restrict__ bias,
                  int M, int N, int K, int epi, size_t zstride)
{
    __shared__ ushort As[2][128 * 64];
    __shared__ ushort Bs[2][128 * 64];
    const int t    = threadIdx.x;
    const int bm   = blockIdx.y << 7, bn = blockIdx.x << 7;
    const int wave = t >> 6, lane = t & 63;
    const int wr   = (wave >> 2) << 6;
    const int wc   = (wave & 3) << 5;
    const int lr   = lane & 15, lh = lane >> 4;
    const int kper  = K / gridDim.z;
    const int kbase = blockIdx.z * kper;
    const int nkt   = kper >> 6;

    const ushort* ga[2]; const ushort* gb[2];
    int ldof[2];
#pragma unroll
    for (int it = 0; it < 2; ++it) {
        const int seg = wave + (it << 3);
        const int row = (seg << 3) + (lane >> 3);
        const int jj  = (lane & 7) ^ ((lane >> 3) & 7);
        ga[it] = A + (size_t)(bm + row) * lda + kbase + jj * 8;
        int gn = bn + row; gn = gn < N ? gn : N - 1;
        gb[it] = B + (size_t)gn * ldb + kbase + jj * 8;
        ldof[it] = seg << 9;
    }

#define STAGE(bsel) do {                                                \
    _Pragma("unroll")                                                   \
    for (int it = 0; it < 2; ++it) {                                    \
        gload16(ga[it], &As[bsel][ldof[it]]);                           \
        gload16(gb[it], &Bs[bsel][ldof[it]]);                           \
        ga[it] += 64; gb[it] += 64;                                     \
    }                                                                   \
} while (0)

    f32x4 acc[4][2];
#pragma unroll
    for (int i = 0; i < 4; ++i)
#pragma unroll
        for (int j = 0; j < 2; ++j) {
            acc[i][j][0] = 0.f; acc[i][j][1] = 0.f;
            acc[i][j][2] = 0.f; acc[i][j][3] = 0.f;
        }

    STAGE(0);
    for (int kt = 0; kt < nkt; ++kt) {
        const int cur = kt & 1;
        if (kt + 1 < nkt) {
            STAGE(cur ^ 1);
            asm volatile("s_waitcnt vmcnt(4)" ::: "memory");
        } else {
            asm volatile("s_waitcnt vmcnt(0)" ::: "memory");
        }
        __builtin_amdgcn_s_barrier();
        __builtin_amdgcn_sched_barrier(0);

        const char* Ab = (const char*)As[cur];
        const char* Bb = (const char*)Bs[cur];
#pragma unroll
        for (int kk = 0; kk < 2; ++kk) {
            bf16x8 af[4], bf[2];
#pragma unroll
            for (int mi = 0; mi < 4; ++mi) {
                const int row = wr + (mi << 4) + lr;
                const int ch  = ((kk << 2) + lh) ^ (row & 7);
                af[mi] = *(const bf16x8*)(Ab + row * 128 + (ch << 4));
            }
#pragma unroll
            for (int nj = 0; nj < 2; ++nj) {
                const int row = wc + (nj << 4) + lr;
                const int ch  = ((kk << 2) + lh) ^ (row & 7);
                bf[nj] = *(const bf16x8*)(Bb + row * 128 + (ch << 4));
            }
#pragma unroll
            for (int mi = 0; mi < 4; ++mi)
#pragma unroll
                for (int nj = 0; nj < 2; ++nj)
                    acc[mi][nj] = __builtin_amdgcn_mfma_f32_16x16x32_bf16(
                        af[mi], bf[nj], acc[mi][nj], 0, 0, 0);
        }
        __builtin_amdgcn_s_barrier();
        __builtin_amdgcn_sched_barrier(0);
    }
#undef STAGE

    float*  C  = (float*)Cv + (size_t)blockIdx.z * zstride;
    ushort* Cb = (ushort*)Cv;
#pragma unroll
    for (int mi = 0; mi < 4; ++mi) {
#pragma unroll
        for (int nj = 0; nj < 2; ++nj) {
            const int col  = bn + wc + (nj << 4) + lr;
            const int row0 = bm + wr + (mi << 4) + (lh << 2);
            if (col < N) {
#pragma unroll
                for (int r = 0; r < 4; ++r) {
                    const float v = acc[mi][nj][r];
                    if (epi == 0)
                        C[(size_t)(row0 + r) * ldc + col] = v;
                    else
                        Cb[(size_t)(row0 + r) * ldc + col] =
                            (ushort)f2bf(softplusf_(v + bias[col]));
                }
            }
        }
    }
}

// ---------------------------------------------------------------------------
__global__ __launch_bounds__(256)
void cvt_bf16(const float* __restrict__ in, ushort* __restrict__ out, int n8)
{
    for (int i = blockIdx.x * 256 + threadIdx.x; i < n8; i += gridDim.x * 256) {
        const float4 v0 = ((const float4*)in)[i * 2];
        const float4 v1 = ((const float4*)in)[i * 2 + 1];
        int4 p;
        p.x = (int)(f2bf(v0.x) | (f2bf(v0.y) << 16));
        p.y = (int)(f2bf(v0.z) | (f2bf(v0.w) << 16));
        p.z = (int)(f2bf(v1.x) | (f2bf(v1.y) << 16));
        p.w = (int)(f2bf(v1.z) | (f2bf(v1.w) << 16));
        ((int4*)out)[i] = p;
    }
}

// ---------------------------------------------------------------------------
__global__ __launch_bounds__(256)
void reduce_out4(const float* __restrict__ part, float* __restrict__ out, int n4)
{
    const int stride = M_TOK * D_MODEL / 4;   // float4 units per slice
    for (int i = blockIdx.x * 256 + threadIdx.x; i < n4; i += gridDim.x * 256) {
        const float4 a = ((const float4*)part)[i];
        const float4 b = ((const float4*)part)[i + stride];
        const float4 c = ((const float4*)part)[i + 2 * stride];
        const float4 d = ((const float4*)part)[i + 3 * stride];
        ((float4*)out)[i] = make_float4(a.x + b.x + c.x + d.x,
                                        a.y + b.y + c.y + d.y,
                                        a.z + b.z + c.z + d.z,
                                        a.w + b.w + c.w + d.w);
    }
}

// ---------------------------------------------------------------------------
// Depthwise causal conv (K=4) + bias + SiLU, m-chunked register window.
// ---------------------------------------------------------------------------
__global__ __launch_bounds__(256)
void conv_silu_k(const ushort* __restrict__ xraw,
                 const float* __restrict__ cw,
                 const float* __restrict__ cb,
                 ushort* __restrict__ xb)
{
    const int d  = (blockIdx.x << 8) + threadIdx.x;
    const int m0 = blockIdx.y << 6;
    const int l0 = m0 & (LSEQ - 1);
    const float4 w = *(const float4*)&cw[d << 2];
    const float bias = cb[d];
    float x3 = 0.f, x2 = 0.f, x1 = 0.f;
    if (l0 > 0) {
        x3 = bf2f(xraw[(size_t)(m0 - 3) * D_INNER + d]);
        x2 = bf2f(xraw[(size_t)(m0 - 2) * D_INNER + d]);
        x1 = bf2f(xraw[(size_t)(m0 - 1) * D_INNER + d]);
    }
#pragma unroll 4
    for (int i = 0; i < 64; ++i) {
        const size_t m = (size_t)m0 + i;
        const float x0 = bf2f(xraw[m * D_INNER + d]);
        float acc = bias;
        acc = fmaf(w.x, x3, acc);
        acc = fmaf(w.y, x2, acc);
        acc = fmaf(w.z, x1, acc);
        acc = fmaf(w.w, x0, acc);
        const float sg = 1.f / (1.f + expf(-acc));
        xb[m * D_INNER + d] = (ushort)f2bf(acc * sg);
        x3 = x2; x2 = x1; x1 = x0;
    }
}

// ---------------------------------------------------------------------------
__global__ __launch_bounds__(256)
void reduce_ssm(const float* __restrict__ part,
                float* __restrict__ ssmf, ushort* __restrict__ ssmb)
{
    const int i = blockIdx.x * 256 + threadIdx.x;
    float v = 0.f;
#pragma unroll
    for (int z = 0; z < 8; ++z) v += part[(size_t)z * (M_TOK * 160) + i];
    ssmf[i] = v;
    ssmb[i] = (ushort)f2bf(v);
}

// ---------------------------------------------------------------------------
// Chunked selective scan: thread owns (b, d, chunk), 16 states in VGPRs.
// ---------------------------------------------------------------------------
__global__ __launch_bounds__(256)
void scan_pass1(const ushort* __restrict__ dtp,
                const ushort* __restrict__ xb,
                const float* __restrict__ ssm,
                const float* __restrict__ Ap,
                float* __restrict__ Pc, float* __restrict__ Qc)
{
    const int d = (blockIdx.x << 8) + threadIdx.x;
    const int c = blockIdx.y, b = blockIdx.z;
    float a[16];
    *(float4*)&a[0]  = *(const float4*)&Ap[d * 16];
    *(float4*)&a[4]  = *(const float4*)&Ap[d * 16 + 4];
    *(float4*)&a[8]  = *(const float4*)&Ap[d * 16 + 8];
    *(float4*)&a[12] = *(const float4*)&Ap[d * 16 + 12];
    float q[16];
#pragma unroll
    for (int s = 0; s < 16; ++s) q[s] = 0.f;
    float dtsum = 0.f;
    const size_t m0 = (size_t)b * LSEQ + (size_t)c * LCHUNK;
#pragma unroll 2
    for (int l = 0; l < LCHUNK; ++l) {
        const size_t m = m0 + l;
        const float dt = bf2f(dtp[m * D_INNER + d]);
        const float xv = bf2f(xb[m * D_INNER + d]);
        const float4 B0 = *(const float4*)&ssm[m * 160 + 128];
        const float4 B1 = *(const float4*)&ssm[m * 160 + 132];
        const float4 B2 = *(const float4*)&ssm[m * 160 + 136];
        const float4 B3 = *(const float4*)&ssm[m * 160 + 140];
        const float Bv[16] = {B0.x,B0.y,B0.z,B0.w, B1.x,B1.y,B1.z,B1.w,
                              B2.x,B2.y,B2.z,B2.w, B3.x,B3.y,B3.z,B3.w};
        const float t1 = dt * xv;
#pragma unroll
        for (int s = 0; s < 16; ++s) {
            const float dA = __expf(dt * a[s]);
            q[s] = fmaf(q[s], dA, t1 * Bv[s]);
        }
        dtsum += dt;
    }
    const size_t o = (((size_t)b * D_INNER + d) * NCHUNK + c) * D_STATE;
    float P[16];
#pragma unroll
    for (int s = 0; s < 16; ++s) P[s] = __expf(a[s] * dtsum);
#pragma unroll
    for (int s4 = 0; s4 < 4; ++s4) {
        *(float4*)&Pc[o + s4 * 4] = make_float4(P[s4*4], P[s4*4+1], P[s4*4+2], P[s4*4+3]);
        *(float4*)&Qc[o + s4 * 4] = make_float4(q[s4*4], q[s4*4+1], q[s4*4+2], q[s4*4+3]);
    }
}

__global__ __launch_bounds__(256)
void scan_pass2(const float* __restrict__ Pc, float* __restrict__ Qc)
{
    const int i = blockIdx.x * 256 + threadIdx.x;
    const size_t base = (size_t)(i >> 4) * (NCHUNK * D_STATE) + (i & 15);
    float st = 0.f;
#pragma unroll
    for (int c = 0; c < NCHUNK; ++c) {
        const float P = Pc[base + c * D_STATE];
        const float q = Qc[base + c * D_STATE];
        Qc[base + c * D_STATE] = st;
        st = fmaf(st, P, q);
    }
}

__global__ __launch_bounds__(256)
void scan_pass3(const ushort* __restrict__ dtp,
                ushort* __restrict__ xb,
                const ushort* __restrict__ gb,
                const float* __restrict__ ssm,
                const float* __restrict__ Ap,
                const float* __restrict__ Qc,
                const float* __restrict__ Dp)
{
    const int d = (blockIdx.x << 8) + threadIdx.x;
    const int c = blockIdx.y, b = blockIdx.z;
    float a[16], st[16];
    *(float4*)&a[0]  = *(const float4*)&Ap[d * 16];
    *(float4*)&a[4]  = *(const float4*)&Ap[d * 16 + 4];
    *(float4*)&a[8]  = *(const float4*)&Ap[d * 16 + 8];
    *(float4*)&a[12] = *(const float4*)&Ap[d * 16 + 12];
    const size_t qo = (((size_t)b * D_INNER + d) * NCHUNK + c) * D_STATE;
    *(float4*)&st[0]  = *(const float4*)&Qc[qo];
    *(float4*)&st[4]  = *(const float4*)&Qc[qo + 4];
    *(float4*)&st[8]  = *(const float4*)&Qc[qo + 8];
    *(float4*)&st[12] = *(const float4*)&Qc[qo + 12];
    const float Dd = Dp[d];
    const size_t m0 = (size_t)b * LSEQ + (size_t)c * LCHUNK;
#pragma unroll 2
    for (int l = 0; l < LCHUNK; ++l) {
        const size_t m = m0 + l;
        const float dt = bf2f(dtp[m * D_INNER + d]);
        const float xv = bf2f(xb[m * D_INNER + d]);
        const float gv = bf2f(gb[m * D_INNER + d]);
        const float4 B0 = *(const float4*)&ssm[m * 160 + 128];
        const float4 B1 = *(const float4*)&ssm[m * 160 + 132];
        const float4 B2 = *(const float4*)&ssm[m * 160 + 136];
        const float4 B3 = *(const float4*)&ssm[m * 160 + 140];
        const float4 C0 = *(const float4*)&ssm[m * 160 + 144];
        const float4 C1 = *(const float4*)&ssm[m * 160 + 148];
        const float4 C2 = *(const float4*)&ssm[m * 160 + 152];
        const float4 C3 = *(const float4*)&ssm[m * 160 + 156];
        const float Bv[16] = {B0.x,B0.y,B0.z,B0.w, B1.x,B1.y,B1.z,B1.w,
                              B2.x,B2.y,B2.z,B2.w, B3.x,B3.y,B3.z,B3.w};
        const float Cv[16] = {C0.x,C0.y,C0.z,C0.w, C1.x,C1.y,C1.z,C1.w,
                              C2.x,C2.y,C2.z,C2.w, C3.x,C3.y,C3.z,C3.w};
        const float t1 = dt * xv;
        float y = 0.f;
#pragma unroll
        for (int s = 0; s < 16; ++s) {
            const float dA = __expf(dt * a[s]);
            st[s] = fmaf(st[s], dA, t1 * Bv[s]);
            y = fmaf(st[s], Cv[s], y);
        }
        const float yg  = fmaf(Dd, xv, y);
        const float sig = 1.f / (1.f + expf(-gv));
        xb[m * D_INNER + d] = (ushort)f2bf(yg * (gv * sig));
    }
}

// ---------------------------------------------------------------------------
extern "C" void kernel_launch(void* const* d_in, const int* in_sizes, int n_in,
                              void* d_out, int out_size, void* d_ws, size_t ws_size,
                              hipStream_t stream)
{
    (void)in_sizes; (void)n_in; (void)out_size; (void)ws_size;
    const float* hs  = (const float*)d_in[0];  // [2048,2048]
    const float* inw = (const float*)d_in[1];  // [8192,2048]
    const float* cw  = (const float*)d_in[2];  // [4096,4]
    const float* cb  = (const float*)d_in[3];  // [4096]
    const float* xw  = (const float*)d_in[4];  // [160,4096]
    const float* dtw = (const float*)d_in[5];  // [4096,128]
    const float* dtb = (const float*)d_in[6];  // [4096]
    const float* Ap  = (const float*)d_in[7];  // [4096,16]
    const float* Dp  = (const float*)d_in[8];  // [4096]
    const float* ow  = (const float*)d_in[9];  // [2048,4096]
    float* out = (float*)d_out;                // [2048,2048]

    // ------------------------------------------------------------------
    // Workspace plan, f32-offset units. ALL bf16 sizes below are f32-EQUIV
    // (= ushort_count / 2), double-checked (r4/r5/r9 bug class):
    //   hsb   2,097,152   inwb  8,388,608   pg/xraw/xtb/owb/dtb16 4,194,304
    //   ssmf 327,680  ssmb 163,840  xwb 327,680  dtwb 262,144
    //   part 2,621,440  Pc/Qc 2,097,152  P 16,777,216
    // Total 25,165,824 f32 = 100.7 MB (<= proven 105 MB).
    // Timeline (single-writer-before-reader, all intervals verified):
    //  1 cvt: hsb[0,2097152) inwb[2097152,10485760)
    //  2 in_proj reads hsb,inwb -> xraw[20971520,25165824) + pg[10485760,14680064)
    //  3 conv reads xraw -> xtb[16777216,20971520)        (xraw dead)
    //  4 cvt: owb[20971520,25165824) over dead xraw; xwb[4194304,4521984),
    //    dtwb[4521984,4784128) over dead inwb
    //  5 x_proj -> part[5275648,7897088); reduce -> ssmf[4784128,5111808)
    //    + ssmb[5111808,5275648)                          (part dead)
    //  6 dt_proj -> dtb16[0,4194304) over dead hsb+inwb-head
    //  7 scan: Pc[5275648,7372800) Qc[7372800,9469952) over dead part;
    //    pass3 reads dtb16,xtb,pg,ssmf,Qc -> y over xtb   (pg,dtb16 die here)
    //  8 out_proj reads xtb,owb -> P[0,16777216) (4 slices); reduce4 -> out
    // ------------------------------------------------------------------
    float*  ws    = (float*)d_ws;
    float*  P     = ws;                          // [0, 16777216)        step 8
    ushort* hsb   = (ushort*)(ws + 0);           // [0, 2097152)         steps 1-2
    ushort* inwb  = (ushort*)(ws + 2097152);     // [2097152, 10485760)  steps 1-2
    ushort* dtb16 = (ushort*)(ws + 0);           // [0, 4194304)         steps 6-7
    ushort* xwb   = (ushort*)(ws + 4194304);     // [4194304, 4521984)   steps 4-5
    ushort* dtwb  = (ushort*)(ws + 4521984);     // [4521984, 4784128)   steps 4-6
    float*  ssmf  = ws + 4784128;                // [4784128, 5111808)   steps 5-7
    ushort* ssmb  = (ushort*)(ws + 5111808);     // [5111808, 5275648)   steps 5-6
    float*  part  = ws + 5275648;                // [5275648, 7897088)   step 5
    float*  Pc    = ws + 5275648;                // [5275648, 7372800)   step 7
    float*  Qc    = ws + 7372800;                // [7372800, 9469952)   step 7
    ushort* pg    = (ushort*)(ws + 10485760);    // [10485760, 14680064) steps 2-7
    ushort* xtb   = (ushort*)(ws + 16777216);    // [16777216, 20971520) steps 3-8
    ushort* xraw  = (ushort*)(ws + 20971520);    // [20971520, 25165824) steps 2-3
    ushort* owb   = (ushort*)(ws + 20971520);    // same region,         steps 4-8

    const dim3 blk(256);
    const dim3 blk512(512);

    // 1) input conversions needed for in_proj
    cvt_bf16<<<dim3(1280), blk, 0, stream>>>(hs,  hsb,  524288);
    cvt_bf16<<<dim3(1280), blk, 0, stream>>>(inw, inwb, 2097152);

    // 2) in_proj (fused x+gate): [2048 x 8192], 8-phase 256^2 engine
    gemm256_8ph<<<dim3(32, 8, 1), blk512, 0, stream>>>(
        hsb, D_MODEL, inwb, D_MODEL, xraw, D_INNER, pg, D_MODEL, 5, 0);

    // 3) conv + SiLU: xraw -> xtb
    conv_silu_k<<<dim3(16, 32), blk, 0, stream>>>(xraw, cw, cb, xtb);

    // 4) remaining weight conversions (hsb, inwb, xraw dead)
    cvt_bf16<<<dim3(1280), blk, 0, stream>>>(ow,  owb, 1048576);
    cvt_bf16<<<dim3(1280), blk, 0, stream>>>(xw,  xwb,  81920);
    cvt_bf16<<<dim3(1280), blk, 0, stream>>>(dtw, dtwb, 65536);

    // 5) x_proj split-K x8 -> part; reduce -> ssmf/ssmb
    gemm_bf16_bt<<<dim3(2, 16, 8), blk512, 0, stream>>>(
        xtb, D_INNER, xwb, D_INNER, part, 160, nullptr,
        M_TOK, 160, D_INNER, 0, (size_t)M_TOK * 160);
    reduce_ssm<<<dim3(1280), blk, 0, stream>>>(part, ssmf, ssmb);

    // 6) dt_proj + softplus(+bias) -> dtb16
    gemm_bf16_bt<<<dim3(32, 16, 1), blk512, 0, stream>>>(
        ssmb, 160, dtwb, DT_RANK, dtb16, D_INNER, dtb,
        M_TOK, D_INNER, DT_RANK, 1, 0);

    // 7) chunked selective scan (+ D-skip + gate), y bf16 over xtb
    scan_pass1<<<dim3(16, NCHUNK, B_SZ), blk, 0, stream>>>(dtb16, xtb, ssmf, Ap, Pc, Qc);
    scan_pass2<<<dim3((B_SZ * D_INNER * D_STATE) / 256), blk, 0, stream>>>(Pc, Qc);
    scan_pass3<<<dim3(16, NCHUNK, B_SZ), blk, 0, stream>>>(dtb16, xtb, pg, ssmf, Ap, Qc, Dp);

    // 8) out_proj: 8-phase 256^2, split-K x4 -> P; reduce4 -> out
    gemm256_8ph<<<dim3(8, 8, 4), blk512, 0, stream>>>(
        xtb, D_INNER, owb, D_INNER, P, D_MODEL, nullptr,
        D_INNER, 0, (size_t)M_TOK * D_MODEL);
    reduce_out4<<<dim3(1024), blk, 0, stream>>>(P, out, (M_TOK * D_MODEL) / 4);
}